// Round 5
// baseline (410.551 us; speedup 1.0000x reference)
//
#include <hip/hip_runtime.h>

typedef float f32x4 __attribute__((ext_vector_type(4)));
typedef __bf16 bf16x8 __attribute__((ext_vector_type(8)));

#define MFMA16(a, b, c) __builtin_amdgcn_mfma_f32_16x16x32_bf16(a, b, c, 0, 0, 0)

constexpr int S = 2048, H = 16, Dh = 64;
#define NEG_INF_F (-1e30f)

// Direct global->LDS DMA, 16B per lane. LDS dest = wave-uniform base + lane*16.
__device__ __forceinline__ void gld16(const __bf16* g, __bf16* l) {
    __builtin_amdgcn_global_load_lds(
        (const __attribute__((address_space(1))) void*)(g),
        (__attribute__((address_space(3))) void*)(l), 16, 0, 0);
}

// Pre-pass: qkv f32 -> khat[bh][t][d] bf16 and vT[bh][d][t] bf16 (transposed),
// both with 8-elem groups XOR-swizzled by (row&7) so fa_fwd's unpadded LDS
// tiles give conflict-free b128 fragment reads after a LINEAR gld16 copy.
__global__ __launch_bounds__(256) void prep(const float* __restrict__ qkv,
                                            __bf16* __restrict__ khat,
                                            __bf16* __restrict__ vT)
{
    __shared__ __bf16 vtile[64][72];
    const int tid = threadIdx.x;
    const int bid = blockIdx.x;          // bh*32 + tt
    const int tt  = bid & 31;
    const int bh  = bid >> 5;            // b*16 + h
    const int b   = bh >> 4, h = bh & 15;
    const int t0  = tt * 64;
    const int tr  = tid >> 2, c0 = (tid & 3) * 16;

    const float* kp = qkv + (((size_t)(b * S + t0 + tr) * 3 + 1) * H + h) * Dh + c0;
    const float* vp = qkv + (((size_t)(b * S + t0 + tr) * 3 + 2) * H + h) * Dh + c0;
    f32x4 k0 = *(const f32x4*)(kp + 0), k1 = *(const f32x4*)(kp + 4),
          k2 = *(const f32x4*)(kp + 8), k3 = *(const f32x4*)(kp + 12);
    f32x4 v0 = *(const f32x4*)(vp + 0), v1 = *(const f32x4*)(vp + 4),
          v2 = *(const f32x4*)(vp + 8), v3 = *(const f32x4*)(vp + 12);
    bf16x8 ka, kb, va, vb;
#pragma unroll
    for (int j = 0; j < 4; ++j) {
        ka[j] = (__bf16)k0[j]; ka[4 + j] = (__bf16)k1[j];
        kb[j] = (__bf16)k2[j]; kb[4 + j] = (__bf16)k3[j];
        va[j] = (__bf16)v0[j]; va[4 + j] = (__bf16)v1[j];
        vb[j] = (__bf16)v2[j]; vb[4 + j] = (__bf16)v3[j];
    }
    {
        __bf16* kd = khat + ((size_t)bh * S + t0 + tr) * Dh;
        const int g0 = c0 >> 3, sw = tr & 7;
        *(bf16x8*)(kd + ((( g0    ) ^ sw) << 3)) = ka;
        *(bf16x8*)(kd + (((g0 + 1) ^ sw) << 3)) = kb;
    }
    *(bf16x8*)&vtile[tr][c0]     = va;
    *(bf16x8*)&vtile[tr][c0 + 8] = vb;
    __syncthreads();
    const int d = tid >> 2, tc0 = (tid & 3) * 16;
    bf16x8 x, y;
#pragma unroll
    for (int i = 0; i < 8; ++i) {
        x[i] = vtile[tc0 + i][d];
        y[i] = vtile[tc0 + 8 + i][d];
    }
    __bf16* vd = vT + ((size_t)bh * Dh + d) * S + t0;
    const int h0 = tc0 >> 3, sv = d & 7;
    *(bf16x8*)(vd + ((( h0    ) ^ sv) << 3)) = x;
    *(bf16x8*)(vd + (((h0 + 1) ^ sv) << 3)) = y;
}

// Block = 8 waves = one (b,h,128-row Q tile); exactly 2 blocks/CU, paired
// qt2 <-> 15-qt2 so every CU sums to 34 iterations. K/V double-buffered in
// LDS via gld16 issued a full compute-phase ahead; ONE barrier per
// iteration (drains next-tile DMA + bias; fences cur-buffer reads).
__global__ __launch_bounds__(512, 4) void fa_fwd(
    const float* __restrict__ qkv, const float* __restrict__ pb,
    const __bf16* __restrict__ khat, const __bf16* __restrict__ vT,
    float* __restrict__ out)
{
    __shared__ __bf16 klds[2][4096];        // [t][d] swizzled, 8KB per buf
    __shared__ __bf16 vlds[2][4096];        // [d][t] swizzled
    __shared__ __bf16 plds[8][16][66];      // per-wave P tile

    const int tid  = threadIdx.x;
    const int wave = tid >> 6;
    const int lane = tid & 63;
    const int quad = lane >> 4;
    const int l16  = lane & 15;

    // 512 blocks; same-CU pair (bid, bid+256) gets qt2 {15-kk, kk} -> equal sums.
    const int g  = blockIdx.x >> 8;
    const int pp = blockIdx.x & 255;
    const int kk = pp >> 5, hb = pp & 31;
    const int b  = hb & 1, h = hb >> 1;
    const int qt2 = g ? kk : 15 - kk;
    const int q0  = qt2 * 128;
    const int bh  = b * H + h;
    const int niter = 2 * qt2 + 2;          // always even
    const float scale = 0.125f;

    // ---- Q fragments (row = q0 + 16*wave + l16) ----
    const int qrow = q0 + wave * 16 + l16;
    const float* qp = qkv + (((size_t)(b * S + qrow) * 3 + 0) * H + h) * Dh;
    bf16x8 qfrag[2];
#pragma unroll
    for (int ks = 0; ks < 2; ++ks) {
        f32x4 a = *(const f32x4*)(qp + ks * 32 + quad * 8);
        f32x4 c = *(const f32x4*)(qp + ks * 32 + quad * 8 + 4);
#pragma unroll
        for (int j = 0; j < 4; ++j) qfrag[ks][j] = (__bf16)a[j];
#pragma unroll
        for (int j = 0; j < 4; ++j) qfrag[ks][4 + j] = (__bf16)c[j];
    }

    const int myrow = q0 + wave * 16 + quad * 4;   // + r
    float l_r[4] = {0.f, 0.f, 0.f, 0.f};
    f32x4 oacc[4];
#pragma unroll
    for (int dt = 0; dt < 4; ++dt) oacc[dt] = (f32x4){0.f, 0.f, 0.f, 0.f};

    // ---- DMA pointers: wave w stages rows [8w, 8w+8) of each 64-row tile ----
    const int lt = lane >> 3, le = (lane & 7) * 8;
    const __bf16* kg = khat + ((size_t)bh * S + wave * 8 + lt) * 64 + le;
    const __bf16* vg = vT + ((size_t)(bh * Dh + wave * 8 + lt)) * S + le;
    const float*  bb = pb + (size_t)h * S * S + (size_t)myrow * S + l16;
    const int swz = l16 & 7;

    float ba[16], bn[16];

    // ---- prologue: tile 0 DMA + bias ----
    gld16(kg, &klds[0][wave * 512]);
    gld16(vg, &vlds[0][wave * 512]);
#pragma unroll
    for (int ct = 0; ct < 4; ++ct)
#pragma unroll
        for (int r = 0; r < 4; ++r) ba[ct * 4 + r] = bb[(size_t)r * S + ct * 16];
    __syncthreads();

    auto step = [&](int it, int cb, float* bcur, float* bnext) {
        // prefetch tile it+1 (alt buffer + bias regs) -- full phase in flight
        if (it + 1 < niter) {
            gld16(kg + (size_t)(it + 1) * 4096, &klds[cb ^ 1][wave * 512]);
            gld16(vg + (it + 1) * 64,           &vlds[cb ^ 1][wave * 512]);
#pragma unroll
            for (int ct = 0; ct < 4; ++ct)
#pragma unroll
                for (int r = 0; r < 4; ++r)
                    bnext[ct * 4 + r] = bb[(size_t)r * S + (it + 1) * 64 + ct * 16];
        }

        // ---- S = Q K^T ----
        f32x4 sacc[4];
#pragma unroll
        for (int ct = 0; ct < 4; ++ct) sacc[ct] = (f32x4){0.f, 0.f, 0.f, 0.f};
#pragma unroll
        for (int ct = 0; ct < 4; ++ct) {
#pragma unroll
            for (int ks = 0; ks < 2; ++ks) {
                bf16x8 kf = *(const bf16x8*)&klds[cb][(ct * 16 + l16) * 64 + (((ks * 4 + quad) ^ swz) << 3)];
                sacc[ct] = MFMA16(qfrag[ks], kf, sacc[ct]);
            }
        }

        // ---- scale + bias (+ causal mask on the 2 diagonal tiles), exp ----
        const bool diag = (it >= niter - 2);
#pragma unroll
        for (int ct = 0; ct < 4; ++ct) {
            const int col = it * 64 + ct * 16 + l16;     // global t
#pragma unroll
            for (int r = 0; r < 4; ++r) {
                float s_ = fmaf(sacc[ct][r], scale, bcur[ct * 4 + r]);
                if (diag && (col > myrow + r)) s_ = NEG_INF_F;
                float p = __expf(s_);
                l_r[r] += p;
                plds[wave][quad * 4 + r][ct * 16 + l16] = (__bf16)p;
            }
        }

        // ---- O += P V ----
        bf16x8 pf[2];
#pragma unroll
        for (int ks = 0; ks < 2; ++ks)
            pf[ks] = *(const bf16x8*)&plds[wave][l16][ks * 32 + quad * 8];
#pragma unroll
        for (int dt = 0; dt < 4; ++dt) {
#pragma unroll
            for (int ks = 0; ks < 2; ++ks) {
                bf16x8 vf = *(const bf16x8*)&vlds[cb][(dt * 16 + l16) * 64 + (((ks * 4 + quad) ^ swz) << 3)];
                oacc[dt] = MFMA16(pf[ks], vf, oacc[dt]);
            }
        }

        // ONE barrier: fences cur-buf reads, drains next-tile DMA + bias loads
        __syncthreads();
    };

    for (int it = 0; it < niter; it += 2) {
        step(it,     0, ba, bn);
        step(it + 1, 1, bn, ba);
    }

    // ---- epilogue: reduce l over the 16-lane row group, normalize, store ----
#pragma unroll
    for (int r = 0; r < 4; ++r) {
#pragma unroll
        for (int m = 1; m < 16; m <<= 1) l_r[r] += __shfl_xor(l_r[r], m, 64);
        const float inv = 1.0f / l_r[r];
        float* op = out + (((size_t)(b * S + (myrow + r)) * H) + h) * Dh;
#pragma unroll
        for (int dt = 0; dt < 4; ++dt)
            op[dt * 16 + l16] = oacc[dt][r] * inv;
    }
}

extern "C" void kernel_launch(void* const* d_in, const int* in_sizes, int n_in,
                              void* d_out, int out_size, void* d_ws, size_t ws_size,
                              hipStream_t stream) {
    const float* qkv = (const float*)d_in[0];
    const float* pb  = (const float*)d_in[1];
    float* out       = (float*)d_out;

    constexpr size_t KV_ELEMS = (size_t)2 * H * S * Dh;   // bf16 elems each
    __bf16* khat = (__bf16*)d_ws;
    __bf16* vT   = khat + KV_ELEMS;

    prep<<<dim3(1024), dim3(256), 0, stream>>>(qkv, khat, vT);
    fa_fwd<<<dim3(512), dim3(512), 0, stream>>>(qkv, pb, khat, vT, out);
}